// Round 8
// baseline (864.110 us; speedup 1.0000x reference)
//
#include <hip/hip_runtime.h>
#include <hip/hip_cooperative_groups.h>

namespace cg = cooperative_groups;

// ---------------- problem constants ----------------
#define N_ANCH 221184      // H*W*A = 128*192*9
#define HW     24576       // H*W
#define Wd     192
#define AA     9
#define TOPN   6000
#define POSTN  300
#define NWORDS 94          // ceil(6016/64) suppression words per row
#define NCHUNK 47          // 6016 / 128
#define GRID   512         // co-resident at 2 blocks/CU (LDS 27.5KB, VGPR<=256)
#define STRIDE0 (GRID * 256)
#define SEGSZ  1024        // compact segment capacity (8 segs = 8192)

typedef unsigned long long u64;

// anchor widths/heights (== ws2/hs2 of the reference, exact small ints)
__device__ const float c_aw[9] = {184.f,368.f,736.f,128.f,256.f,512.f, 88.f,176.f,352.f};
__device__ const float c_ah[9] = { 96.f,192.f,384.f,128.f,256.f,512.f,176.f,352.f,704.f};

// shared box decode — identical FP sequence wherever a box is materialized.
// No FMA contraction (numpy rounds mul and add separately).
__device__ __forceinline__ float4 decode_box(int a, int cell,
                                             const float* __restrict__ deltas,
                                             float info0, float info1, float info2,
                                             bool* valid) {
    int h = cell / Wd;
    int w = cell - h * Wd;
    const float* db = deltas + (size_t)(4 * a) * HW + cell;
    float dx = db[0];
    float dy = db[HW];
    float dw = db[2 * HW];
    float dh = db[3 * HW];
    dw = fminf(fmaxf(dw, -10.f), 10.f);
    dh = fminf(fmaxf(dh, -10.f), 10.f);

    float ww = c_aw[a], hh = c_ah[a];
    float cx = 16.f * (float)w + 8.f;   // exact
    float cy = 16.f * (float)h + 8.f;   // exact

    float pcx = __fadd_rn(__fmul_rn(dx, ww), cx);
    float pcy = __fadd_rn(__fmul_rn(dy, hh), cy);
    float pw  = __fmul_rn(expf(dw), ww);
    float ph  = __fmul_rn(expf(dh), hh);
    float hpw = __fmul_rn(0.5f, pw);
    float hph = __fmul_rn(0.5f, ph);
    float x1 = __fsub_rn(pcx, hpw);
    float x2 = __fadd_rn(pcx, hpw);
    float y1 = __fsub_rn(pcy, hph);
    float y2 = __fadd_rn(pcy, hph);

    float xmax = __fsub_rn(info1, 1.f);
    float ymax = __fsub_rn(info0, 1.f);
    x1 = fminf(fmaxf(x1, 0.f), xmax);
    x2 = fminf(fmaxf(x2, 0.f), xmax);
    y1 = fminf(fmaxf(y1, 0.f), ymax);
    y2 = fminf(fmaxf(y2, 0.f), ymax);

    float msz = __fmul_rn(16.f, info2);
    *valid = (__fadd_rn(__fsub_rn(x2, x1), 1.f) >= msz) &&
             (__fadd_rn(__fsub_rn(y2, y1), 1.f) >= msz);
    return make_float4(x1, y1, x2, y2);
}

// 64-bit readlane, wave-uniform index
__device__ __forceinline__ u64 rdl64(u64 v, int l) {
    unsigned int lo = (unsigned int)__builtin_amdgcn_readlane((int)(unsigned int)v, l);
    unsigned int hi = (unsigned int)__builtin_amdgcn_readlane((int)(unsigned int)(v >> 32), l);
    return ((u64)hi << 32) | (u64)lo;
}

// phase: -1 = fused (cooperative, grid.sync between phases); 0..7 = single phase
__global__ __launch_bounds__(256, 2) void fused_kernel(
        const float* __restrict__ scores, const float* __restrict__ deltas,
        const float* __restrict__ iminfo, float* __restrict__ out,
        unsigned int* __restrict__ keys, unsigned int* __restrict__ slab,
        unsigned int* __restrict__ slab2, unsigned int* __restrict__ state,
        u64* __restrict__ cand, float4* __restrict__ tb,
        u64* __restrict__ vmask, u64* __restrict__ mat, int phase) {
    const bool all = (phase < 0);
    int tid = threadIdx.x;
    int bid = blockIdx.x;
    int lane = tid & 63;
    int wv = tid >> 6;

    __shared__ unsigned int lh[256];
    __shared__ unsigned int sfx[256];
    __shared__ unsigned int h2w[4][256];
    __shared__ u64 stage[2048];          // 16 KB staging (rank phase)
    __shared__ float4 cbw[4][64];        // per-wave col boxes (matrix phase)
    __shared__ int kept[POSTN];          // scan phase

    float info0 = iminfo[0], info1 = iminfo[1], info2 = iminfo[2];

    // ---------- P0: decode keys + per-block top-byte hist slab ----------
    if (all || phase == 0) {
        lh[tid] = 0u;
        __syncthreads();
        #pragma unroll
        for (int j = 0; j < 2; ++j) {
            int t = j * STRIDE0 + bid * 256 + tid;
            if (t < N_ANCH) {
                int a = t / HW;
                int cell = t - a * HW;
                float score = scores[(AA + a) * HW + cell];
                bool valid;
                (void)decode_box(a, cell, deltas, info0, info1, info2, &valid);
                unsigned int sb = __float_as_uint(score);
                unsigned int key = valid ? ((sb & 0x80000000u) ? ~sb : (sb | 0x80000000u))
                                         : 0x007FFFFFu;
                keys[t] = key;
                atomicAdd(&lh[key >> 24], 1u);
            }
        }
        __syncthreads();
        slab[bid * 256 + tid] = lh[tid];
    }
    if (all) { __threadfence(); cg::this_grid().sync(); }

    // ---------- P1: top-byte suffix -> prefix P + rank; zero state/vmask ----
    if ((all && bid == 0) || phase == 1) {
        state[tid] = 0u;
        state[256 + tid] = 0u;
        if (tid < 96) vmask[tid] = 0ull;
        unsigned int s = 0;
        for (int b = 0; b < GRID; ++b) s += slab[b * 256 + tid];
        sfx[tid] = s;
        __syncthreads();
        for (int d = 1; d < 256; d <<= 1) {
            unsigned int v = (tid + d < 256) ? sfx[tid + d] : 0u;
            __syncthreads();
            sfx[tid] += v;
            __syncthreads();
        }
        unsigned int ge = sfx[tid];
        unsigned int gt = (tid < 255) ? sfx[tid + 1] : 0u;
        if (ge >= TOPN && gt < TOPN) { state[1] = (unsigned int)tid; state[2] = TOPN - gt; }
    }
    if (all) { __threadfence(); cg::this_grid().sync(); }

    // ---------- P2: second-byte hist of prefix-P keys (parallel) ----------
    if (all || phase == 2) {
        for (int i = tid; i < 4 * 256; i += 256) ((unsigned int*)h2w)[i] = 0u;
        __syncthreads();
        unsigned int P = *(volatile unsigned int*)&state[1];
        #pragma unroll
        for (int j = 0; j < 2; ++j) {
            int t = j * STRIDE0 + bid * 256 + tid;
            if (t < N_ANCH) {
                unsigned int k = keys[t];
                if ((k >> 24) == P) atomicAdd(&h2w[wv][(k >> 16) & 0xFFu], 1u);
            }
        }
        __syncthreads();
        slab2[bid * 256 + tid] = h2w[0][tid] + h2w[1][tid] + h2w[2][tid] + h2w[3][tid];
    }
    if (all) { __threadfence(); cg::this_grid().sync(); }

    // ---------- P3: second-byte suffix -> 16-bit threshold T ----------
    if ((all && bid == 0) || phase == 3) {
        unsigned int P = *(volatile unsigned int*)&state[1];
        unsigned int rankP = *(volatile unsigned int*)&state[2];
        unsigned int s = 0;
        for (int b = 0; b < GRID; ++b) s += slab2[b * 256 + tid];
        sfx[tid] = s;
        __syncthreads();
        for (int d = 1; d < 256; d <<= 1) {
            unsigned int v = (tid + d < 256) ? sfx[tid + d] : 0u;
            __syncthreads();
            sfx[tid] += v;
            __syncthreads();
        }
        unsigned int ge = sfx[tid];
        unsigned int gt = (tid < 255) ? sfx[tid + 1] : 0u;
        if (ge >= rankP && gt < rankP)
            state[0] = (P << 24) | ((unsigned int)tid << 16);
    }
    if (all) { __threadfence(); cg::this_grid().sync(); }

    // ---------- P4: compact keys >= T into 8 segments ----------
    if (all || phase == 4) {
        unsigned int T = *(volatile unsigned int*)&state[0];
        #pragma unroll
        for (int j = 0; j < 2; ++j) {
            int t = j * STRIDE0 + bid * 256 + tid;
            if (t < N_ANCH) {
                unsigned int k = keys[t];
                if (k >= T) {
                    int seg = bid & 7;
                    unsigned int pos = atomicAdd(&state[32 + 32 * seg], 1u);
                    if (pos < SEGSZ) {
                        int a = t / HW;
                        int cell = t - a * HW;
                        unsigned int aidx = (unsigned int)(cell * 9 + a);
                        cand[seg * SEGSZ + pos] = ((u64)k << 32) | (u64)(~aidx);
                    }
                }
            }
        }
    }
    if (all) { __threadfence(); cg::this_grid().sync(); }

    // ---------- P5: exact rank + scatter (512 blocks x 16 cand) ----------
    if (all || phase == 5) {
        unsigned int cc[8];
        #pragma unroll
        for (int s = 0; s < 8; ++s) {
            cc[s] = *(volatile unsigned int*)&state[32 + 32 * s];
            if (cc[s] > SEGSZ) cc[s] = SEGSZ;
        }
        int part = tid & 15;
        int i = bid * 16 + (tid >> 4);          // [0, 8192)
        int iseg = i >> 10, ioff = i & 1023;
        bool active = (unsigned int)ioff < cc[iseg];
        u64 k = active ? cand[i] : 0ull;
        unsigned int cnt = 0;
        for (int q = 0; q < 4; ++q) {
            for (int j = tid; j < 2048; j += 256) {
                int g = q * 2048 + j;
                int s_ = g >> 10, off = g & 1023;
                stage[j] = ((unsigned int)off < cc[s_]) ? cand[g] : 0ull;
            }
            __syncthreads();
            const ulonglong2* sv = (const ulonglong2*)stage;
            for (int jj = part; jj < 1024; jj += 16) {
                ulonglong2 v = sv[jj];
                cnt += (v.x > k) ? 1u : 0u;
                cnt += (v.y > k) ? 1u : 0u;
            }
            __syncthreads();
        }
        cnt += __shfl_xor(cnt, 1);
        cnt += __shfl_xor(cnt, 2);
        cnt += __shfl_xor(cnt, 4);
        cnt += __shfl_xor(cnt, 8);
        if (part == 0 && active && cnt < TOPN) {
            unsigned int aidx = ~((unsigned int)k);
            int a = (int)(aidx % 9u);
            int cell = (int)(aidx / 9u);
            bool valid;
            float4 box = decode_box(a, cell, deltas, info0, info1, info2, &valid);
            tb[cnt] = box;
            if ((unsigned int)(k >> 32) != 0x007FFFFFu)
                atomicOr(&vmask[cnt >> 6], 1ull << (cnt & 63));
        }
    }
    if (all) { __threadfence(); cg::this_grid().sync(); }

    // ---------- P6: suppression bit-matrix (upper-triangle tiles) ----------
    if (all || phase == 6) {
        int waveid = bid * 4 + wv;
        int wstride = gridDim.x * 4;
        for (int j = waveid; j < 94 * 94; j += wstride) {
            int by = j / 94;
            int bx = j - by * 94;
            if (bx < by) continue;
            int c0 = bx * 64;
            {
                int col = c0 + lane;
                cbw[wv][lane] = (col < TOPN) ? tb[col] : make_float4(0.f, 0.f, 0.f, 0.f);
            }
            int row = by * 64 + lane;
            if (row < TOPN) {
                float4 rb = tb[row];
                float rA = (rb.z - rb.x) * (rb.w - rb.y);
                u64 mask = 0ull;
                for (int c = 0; c < 64; ++c) {
                    if (c0 + c >= TOPN) break;
                    float4 b = cbw[wv][c];
                    float lx = fmaxf(rb.x, b.x), ly = fmaxf(rb.y, b.y);
                    float rx = fminf(rb.z, b.z), ry = fminf(rb.w, b.w);
                    float iw = fmaxf(rx - lx, 0.f), ih = fmaxf(ry - ly, 0.f);
                    float inter = iw * ih;
                    float bA = (b.z - b.x) * (b.w - b.y);
                    float iou = inter / ((rA + bA) - inter);
                    if (iou > 0.7f) mask |= (1ull << c);   // NaN -> false, as numpy
                }
                mat[(size_t)row * NWORDS + bx] = mask;
            }
        }
    }
    if (all) { __threadfence(); cg::this_grid().sync(); }

    // ---------- P7: greedy scan (block 0, wave 0) ----------
    if (((all && bid == 0) || phase == 7) && tid < 64) {
        u64 r0 = ~vmask[lane];
        u64 r1 = (lane < NWORDS - 64) ? ~vmask[64 + lane] : ~0ull;
        int cnt = 0;
        for (int c = 0; c < NCHUNK; ++c) {
            int w2 = 2 * c;
            u64 s0 = (w2 < 64) ? rdl64(r0, w2) : rdl64(r1, w2 - 64);
            u64 s1 = (w2 + 1 < 64) ? rdl64(r0, w2 + 1) : rdl64(r1, w2 + 1 - 64);
            if ((s0 & s1) == ~0ull) continue;      // dead chunk: no memory touched
            int base = c * 128;
            ulonglong2 vA = *(const ulonglong2*)(mat + (size_t)(base + lane) * NWORDS + w2);
            ulonglong2 vB = *(const ulonglong2*)(mat + (size_t)(base + 64 + lane) * NWORDS + w2);
            u64 rem0 = s0, rem1 = s1, k0 = 0ull, k1 = 0ull;
            while (cnt < POSTN) {
                int b;
                if (~rem0) b = __ffsll((u64)~rem0) - 1;
                else if (~rem1) b = 64 + __ffsll((u64)~rem1) - 1;
                else break;
                if (lane == 0) kept[cnt] = base + b;
                ++cnt;
                if (b < 64) {
                    rem0 |= rdl64(vA.x, b) | (1ull << b);
                    rem1 |= rdl64(vA.y, b);
                    k0 |= 1ull << b;
                } else {
                    int bb = b - 64;
                    rem0 |= rdl64(vB.x, bb);
                    rem1 |= rdl64(vB.y, bb) | (1ull << bb);
                    k1 |= 1ull << bb;
                }
            }
            if (cnt >= POSTN) break;
            u64 f0 = 0ull, f1 = 0ull, m0 = k0, m1 = k1;
            while (m0 | m1) {
                int idx[16];
                #pragma unroll
                for (int j = 0; j < 16; ++j) {
                    int b = -1;
                    if (m0) { b = __ffsll(m0) - 1; m0 &= m0 - 1; }
                    else if (m1) { b = 64 + __ffsll(m1) - 1; m1 &= m1 - 1; }
                    idx[j] = b;
                }
                u64 v0[16], v1[16];
                #pragma unroll
                for (int j = 0; j < 16; ++j) {
                    v0[j] = 0ull; v1[j] = 0ull;
                    if (idx[j] >= 0) {
                        const u64* row = mat + (size_t)(base + idx[j]) * NWORDS;
                        v0[j] = row[lane];
                        if (lane < NWORDS - 64) v1[j] = row[64 + lane];
                    }
                }
                #pragma unroll
                for (int j = 0; j < 16; ++j) { f0 |= v0[j]; f1 |= v1[j]; }
            }
            r0 |= f0; r1 |= f1;
        }
        for (int r = lane; r < POSTN; r += 64) {
            float4 b2 = make_float4(0.f, 0.f, 0.f, 0.f);
            if (r < cnt) b2 = tb[kept[r]];
            float* o = out + r * 5;
            o[0] = 0.f; o[1] = b2.x; o[2] = b2.y; o[3] = b2.z; o[4] = b2.w;
        }
    }
}

// ---------------- host launcher ----------------
extern "C" void kernel_launch(void* const* d_in, const int* in_sizes, int n_in,
                              void* d_out, int out_size, void* d_ws, size_t ws_size,
                              hipStream_t stream) {
    const float* scores = (const float*)d_in[0];
    const float* deltas = (const float*)d_in[1];
    const float* iminfo = (const float*)d_in[2];
    float* out = (float*)d_out;

    char* ws = (char*)d_ws;
    // workspace layout (16B-aligned), total 6,621,952 bytes
    unsigned int* keys  = (unsigned int*)(ws + 0);          // 884736
    unsigned int* slab  = (unsigned int*)(ws + 884736);     // 512*256*4 = 524288
    unsigned int* slab2 = (unsigned int*)(ws + 1409024);    // 524288
    unsigned int* state = (unsigned int*)(ws + 1933312);    // 2048
    u64*          cand  = (u64*)(ws + 1935360);             // 65536
    float4*       tb    = (float4*)(ws + 2000896);          // 96256
    u64*          vmask = (u64*)(ws + 2097152);             // 768
    u64*          mat   = (u64*)(ws + 2097920);             // 6016*94*8 = 4524032

    int phase_all = -1;
    void* args[] = { (void*)&scores, (void*)&deltas, (void*)&iminfo, (void*)&out,
                     (void*)&keys, (void*)&slab, (void*)&slab2, (void*)&state,
                     (void*)&cand, (void*)&tb, (void*)&vmask, (void*)&mat,
                     (void*)&phase_all };
    hipError_t err = hipLaunchCooperativeKernel((void*)fused_kernel, dim3(GRID),
                                                dim3(256), args, 0, stream);
    if (err != hipSuccess) {
        (void)hipGetLastError();   // clear sticky error, run phase-split path
        fused_kernel<<<GRID, 256, 0, stream>>>(scores, deltas, iminfo, out, keys, slab,
                                               slab2, state, cand, tb, vmask, mat, 0);
        fused_kernel<<<1,    256, 0, stream>>>(scores, deltas, iminfo, out, keys, slab,
                                               slab2, state, cand, tb, vmask, mat, 1);
        fused_kernel<<<GRID, 256, 0, stream>>>(scores, deltas, iminfo, out, keys, slab,
                                               slab2, state, cand, tb, vmask, mat, 2);
        fused_kernel<<<1,    256, 0, stream>>>(scores, deltas, iminfo, out, keys, slab,
                                               slab2, state, cand, tb, vmask, mat, 3);
        fused_kernel<<<GRID, 256, 0, stream>>>(scores, deltas, iminfo, out, keys, slab,
                                               slab2, state, cand, tb, vmask, mat, 4);
        fused_kernel<<<GRID, 256, 0, stream>>>(scores, deltas, iminfo, out, keys, slab,
                                               slab2, state, cand, tb, vmask, mat, 5);
        fused_kernel<<<GRID, 256, 0, stream>>>(scores, deltas, iminfo, out, keys, slab,
                                               slab2, state, cand, tb, vmask, mat, 6);
        fused_kernel<<<1,    256, 0, stream>>>(scores, deltas, iminfo, out, keys, slab,
                                               slab2, state, cand, tb, vmask, mat, 7);
    }
}

// Round 9
// 276.177 us; speedup vs baseline: 3.1288x; 3.1288x over previous
//
#include <hip/hip_runtime.h>

// ---------------- problem constants ----------------
#define N_ANCH 221184      // H*W*A = 128*192*9
#define HW     24576       // H*W
#define Wd     192
#define AA     9
#define TOPN   6000
#define POSTN  300
#define NWORDS 94          // ceil(6016/64) suppression words per row
#define NCHUNK 47          // 6016 / 128
#define GRID   512
#define GSTRIDE (GRID * 256)
#define SEGSZ  1024        // compact segment capacity (8 segs = 8192)
#define CAND_CAP 8192

typedef unsigned long long u64;
typedef unsigned int u32;

// anchor widths/heights (== ws2/hs2 of the reference, exact small ints)
__device__ const float c_aw[9] = {184.f,368.f,736.f,128.f,256.f,512.f, 88.f,176.f,352.f};
__device__ const float c_ah[9] = { 96.f,192.f,384.f,128.f,256.f,512.f,176.f,352.f,704.f};

// ---- agent-scope (device) atomics: L2-bypassing, L3 is the coherence point
__device__ __forceinline__ u32 ald32(const u32* p) {
    return __hip_atomic_load((const u32*)p, __ATOMIC_RELAXED, __HIP_MEMORY_SCOPE_AGENT);
}
__device__ __forceinline__ void ast32(u32* p, u32 v) {
    __hip_atomic_store(p, v, __ATOMIC_RELAXED, __HIP_MEMORY_SCOPE_AGENT);
}
__device__ __forceinline__ u64 ald64(const u64* p) {
    return __hip_atomic_load((const u64*)p, __ATOMIC_RELAXED, __HIP_MEMORY_SCOPE_AGENT);
}
__device__ __forceinline__ void ast64(u64* p, u64 v) {
    __hip_atomic_store(p, v, __ATOMIC_RELAXED, __HIP_MEMORY_SCOPE_AGENT);
}
__device__ __forceinline__ void stf4(float4* p, float4 v) {
    u64 lo, hi;
    float2 a = make_float2(v.x, v.y), b = make_float2(v.z, v.w);
    __builtin_memcpy(&lo, &a, 8); __builtin_memcpy(&hi, &b, 8);
    ast64((u64*)p, lo); ast64(((u64*)p) + 1, hi);
}
__device__ __forceinline__ float4 ldf4(const float4* p) {
    u64 lo = ald64((const u64*)p), hi = ald64(((const u64*)p) + 1);
    float2 a, b;
    __builtin_memcpy(&a, &lo, 8); __builtin_memcpy(&b, &hi, 8);
    return make_float4(a.x, a.y, b.x, b.y);
}

// lightweight grid barrier: no cache fences needed (all cross-phase data is
// agent-scope). __syncthreads drains vmcnt per wave -> stores are L3-visible
// before the counter bump. Bounded spin turns any bug into wrong-answer.
__device__ __forceinline__ void gbar(u32* bar, u32 target) {
    __syncthreads();
    if (threadIdx.x == 0) {
        __hip_atomic_fetch_add(bar, 1u, __ATOMIC_RELAXED, __HIP_MEMORY_SCOPE_AGENT);
        int guard = 0;
        while (__hip_atomic_load(bar, __ATOMIC_RELAXED, __HIP_MEMORY_SCOPE_AGENT) < target) {
            __builtin_amdgcn_s_sleep(1);
            if (++guard > (1 << 22)) break;
        }
    }
    __syncthreads();
}

// shared box decode — identical FP sequence wherever a box is materialized.
// No FMA contraction (numpy rounds mul and add separately).
__device__ __forceinline__ float4 decode_box(int a, int cell,
                                             const float* __restrict__ deltas,
                                             float info0, float info1, float info2,
                                             bool* valid) {
    int h = cell / Wd;
    int w = cell - h * Wd;
    const float* db = deltas + (size_t)(4 * a) * HW + cell;
    float dx = db[0];
    float dy = db[HW];
    float dw = db[2 * HW];
    float dh = db[3 * HW];
    dw = fminf(fmaxf(dw, -10.f), 10.f);
    dh = fminf(fmaxf(dh, -10.f), 10.f);

    float ww = c_aw[a], hh = c_ah[a];
    float cx = 16.f * (float)w + 8.f;   // exact
    float cy = 16.f * (float)h + 8.f;   // exact

    float pcx = __fadd_rn(__fmul_rn(dx, ww), cx);
    float pcy = __fadd_rn(__fmul_rn(dy, hh), cy);
    float pw  = __fmul_rn(expf(dw), ww);
    float ph  = __fmul_rn(expf(dh), hh);
    float hpw = __fmul_rn(0.5f, pw);
    float hph = __fmul_rn(0.5f, ph);
    float x1 = __fsub_rn(pcx, hpw);
    float x2 = __fadd_rn(pcx, hpw);
    float y1 = __fsub_rn(pcy, hph);
    float y2 = __fadd_rn(pcy, hph);

    float xmax = __fsub_rn(info1, 1.f);
    float ymax = __fsub_rn(info0, 1.f);
    x1 = fminf(fmaxf(x1, 0.f), xmax);
    x2 = fminf(fmaxf(x2, 0.f), xmax);
    y1 = fminf(fmaxf(y1, 0.f), ymax);
    y2 = fminf(fmaxf(y2, 0.f), ymax);

    float msz = __fmul_rn(16.f, info2);
    *valid = (__fadd_rn(__fsub_rn(x2, x1), 1.f) >= msz) &&
             (__fadd_rn(__fsub_rn(y2, y1), 1.f) >= msz);
    return make_float4(x1, y1, x2, y2);
}

// 64-bit readlane, wave-uniform index
__device__ __forceinline__ u64 rdl64(u64 v, int l) {
    u32 lo = (u32)__builtin_amdgcn_readlane((int)(u32)v, l);
    u32 hi = (u32)__builtin_amdgcn_readlane((int)(u32)(v >> 32), l);
    return ((u64)hi << 32) | (u64)lo;
}

__global__ __launch_bounds__(256, 2) void fused_kernel(
        const float* __restrict__ scores, const float* __restrict__ deltas,
        const float* __restrict__ iminfo, float* __restrict__ out,
        u32* __restrict__ bar, u32* __restrict__ hist1, u32* __restrict__ hist2,
        u32* __restrict__ segctr, u64* __restrict__ vmask,
        u32* __restrict__ keys, u64* __restrict__ cand,
        float4* __restrict__ tb, u64* __restrict__ mat) {
    int tid = threadIdx.x;
    int bid = blockIdx.x;
    int lane = tid & 63;
    int wv = tid >> 6;

    __shared__ u32 lh[256];
    __shared__ u32 sfx[256];
    __shared__ u32 h2w[4][256];
    __shared__ u64 stage[2048];          // 16 KB (rank phase)
    __shared__ float4 cbw[4][64];        // matrix phase
    __shared__ int kept[POSTN];          // scan phase
    __shared__ u32 sP, sRank, sT;

    float info0 = iminfo[0], info1 = iminfo[1], info2 = iminfo[2];

    // ---------- P0: decode keys + global 256-bin hist (LDS-aggregated) ------
    lh[tid] = 0u;
    __syncthreads();
    #pragma unroll
    for (int j = 0; j < 2; ++j) {
        int t = j * GSTRIDE + bid * 256 + tid;
        if (t < N_ANCH) {
            int a = t / HW;
            int cell = t - a * HW;
            float score = scores[(AA + a) * HW + cell];
            bool valid;
            (void)decode_box(a, cell, deltas, info0, info1, info2, &valid);
            u32 sb = __float_as_uint(score);
            u32 key = valid ? ((sb & 0x80000000u) ? ~sb : (sb | 0x80000000u))
                            : 0x007FFFFFu;
            ast32(&keys[t], key);
            atomicAdd(&lh[key >> 24], 1u);
        }
    }
    __syncthreads();
    if (lh[tid]) atomicAdd(&hist1[tid], lh[tid]);
    gbar(bar, 1 * GRID);

    // ---------- P1 (redundant per block): suffix hist1 -> prefix P, rankP ---
    sfx[tid] = ald32(&hist1[tid]);
    __syncthreads();
    for (int d = 1; d < 256; d <<= 1) {
        u32 v = (tid + d < 256) ? sfx[tid + d] : 0u;
        __syncthreads();
        sfx[tid] += v;
        __syncthreads();
    }
    {
        u32 ge = sfx[tid];
        u32 gt = (tid < 255) ? sfx[tid + 1] : 0u;
        if (ge >= TOPN && gt < TOPN) { sP = (u32)tid; sRank = TOPN - gt; }
    }
    // ---------- P2: second-byte hist of prefix-P keys -> global hist2 -------
    for (int i = tid; i < 4 * 256; i += 256) ((u32*)h2w)[i] = 0u;
    __syncthreads();
    u32 P = sP, rankP = sRank;
    #pragma unroll
    for (int j = 0; j < 2; ++j) {
        int t = j * GSTRIDE + bid * 256 + tid;
        if (t < N_ANCH) {
            u32 k = ald32(&keys[t]);
            if ((k >> 24) == P) atomicAdd(&h2w[wv][(k >> 16) & 0xFFu], 1u);
        }
    }
    __syncthreads();
    {
        u32 s4 = h2w[0][tid] + h2w[1][tid] + h2w[2][tid] + h2w[3][tid];
        if (s4) atomicAdd(&hist2[tid], s4);
    }
    gbar(bar, 2 * GRID);

    // ---------- P3 (redundant per block): suffix hist2 -> threshold T -------
    sfx[tid] = ald32(&hist2[tid]);
    __syncthreads();
    for (int d = 1; d < 256; d <<= 1) {
        u32 v = (tid + d < 256) ? sfx[tid + d] : 0u;
        __syncthreads();
        sfx[tid] += v;
        __syncthreads();
    }
    {
        u32 ge = sfx[tid];
        u32 gt = (tid < 255) ? sfx[tid + 1] : 0u;
        if (ge >= rankP && gt < rankP) sT = (P << 24) | ((u32)tid << 16);
    }
    __syncthreads();
    u32 T = sT;
    // ---------- P4: compact keys >= T into 8 segments ----------
    #pragma unroll
    for (int j = 0; j < 2; ++j) {
        int t = j * GSTRIDE + bid * 256 + tid;
        if (t < N_ANCH) {
            u32 k = ald32(&keys[t]);
            if (k >= T) {
                int seg = bid & 7;
                u32 pos = atomicAdd(&segctr[32 * seg], 1u);
                if (pos < SEGSZ) {
                    int a = t / HW;
                    int cell = t - a * HW;
                    u32 aidx = (u32)(cell * 9 + a);
                    ast64(&cand[seg * SEGSZ + pos], ((u64)k << 32) | (u64)(~aidx));
                }
            }
        }
    }
    gbar(bar, 3 * GRID);

    // ---------- P5: exact rank + scatter (512 blocks x 16 cand) ----------
    {
        u32 cc[8];
        #pragma unroll
        for (int s = 0; s < 8; ++s) {
            cc[s] = ald32(&segctr[32 * s]);
            if (cc[s] > SEGSZ) cc[s] = SEGSZ;
        }
        int part = tid & 15;
        int i = bid * 16 + (tid >> 4);          // [0, 8192)
        int iseg = i >> 10, ioff = i & 1023;
        bool active = (u32)ioff < cc[iseg];
        u64 k = active ? ald64(&cand[i]) : 0ull;
        u32 cnt = 0;
        for (int q = 0; q < 4; ++q) {
            for (int j = tid; j < 2048; j += 256) {
                int g = q * 2048 + j;
                int s_ = g >> 10, off = g & 1023;
                stage[j] = ((u32)off < cc[s_]) ? ald64(&cand[g]) : 0ull;
            }
            __syncthreads();
            const ulonglong2* sv = (const ulonglong2*)stage;
            for (int jj = part; jj < 1024; jj += 16) {
                ulonglong2 v = sv[jj];
                cnt += (v.x > k) ? 1u : 0u;
                cnt += (v.y > k) ? 1u : 0u;
            }
            __syncthreads();
        }
        cnt += __shfl_xor(cnt, 1);
        cnt += __shfl_xor(cnt, 2);
        cnt += __shfl_xor(cnt, 4);
        cnt += __shfl_xor(cnt, 8);
        if (part == 0 && active && cnt < TOPN) {
            u32 aidx = ~((u32)k);
            int a = (int)(aidx % 9u);
            int cell = (int)(aidx / 9u);
            bool valid;
            float4 box = decode_box(a, cell, deltas, info0, info1, info2, &valid);
            stf4(&tb[cnt], box);
            if ((u32)(k >> 32) != 0x007FFFFFu)
                atomicOr(&vmask[cnt >> 6], 1ull << (cnt & 63));
        }
    }
    gbar(bar, 4 * GRID);

    // ---------- P6: suppression bit-matrix (upper-triangle tiles) ----------
    {
        int waveid = bid * 4 + wv;
        for (int j = waveid; j < 94 * 94; j += GRID * 4) {
            int by = j / 94;
            int bx = j - by * 94;
            if (bx < by) continue;
            int c0 = bx * 64;
            {
                int col = c0 + lane;
                cbw[wv][lane] = (col < TOPN) ? ldf4(&tb[col]) : make_float4(0.f, 0.f, 0.f, 0.f);
            }
            int row = by * 64 + lane;
            if (row < TOPN) {
                float4 rb = ldf4(&tb[row]);
                float rA = (rb.z - rb.x) * (rb.w - rb.y);
                u64 mask = 0ull;
                for (int c = 0; c < 64; ++c) {
                    if (c0 + c >= TOPN) break;
                    float4 b = cbw[wv][c];
                    float lx = fmaxf(rb.x, b.x), ly = fmaxf(rb.y, b.y);
                    float rx = fminf(rb.z, b.z), ry = fminf(rb.w, b.w);
                    float iw = fmaxf(rx - lx, 0.f), ih = fmaxf(ry - ly, 0.f);
                    float inter = iw * ih;
                    float bA = (b.z - b.x) * (b.w - b.y);
                    float iou = inter / ((rA + bA) - inter);
                    if (iou > 0.7f) mask |= (1ull << c);   // NaN -> false, as numpy
                }
                ast64(&mat[(size_t)row * NWORDS + bx], mask);
            }
        }
    }
    gbar(bar, 5 * GRID);

    // ---------- P7: greedy scan (block 0, wave 0) ----------
    if (bid == 0 && tid < 64) {
        u64 r0 = ~ald64(&vmask[lane]);
        u64 r1 = (lane < NWORDS - 64) ? ~ald64(&vmask[64 + lane]) : ~0ull;
        int cnt = 0;
        for (int c = 0; c < NCHUNK; ++c) {
            int w2 = 2 * c;
            u64 s0 = (w2 < 64) ? rdl64(r0, w2) : rdl64(r1, w2 - 64);
            u64 s1 = (w2 + 1 < 64) ? rdl64(r0, w2 + 1) : rdl64(r1, w2 + 1 - 64);
            if ((s0 & s1) == ~0ull) continue;      // dead chunk: no memory touched
            int base = c * 128;
            const u64* rowA = mat + (size_t)(base + lane) * NWORDS + w2;
            const u64* rowB = mat + (size_t)(base + 64 + lane) * NWORDS + w2;
            u64 ax = ald64(rowA), ay = ald64(rowA + 1);
            u64 bx_ = ald64(rowB), by_ = ald64(rowB + 1);
            u64 rem0 = s0, rem1 = s1, k0 = 0ull, k1 = 0ull;
            while (cnt < POSTN) {
                int b;
                if (~rem0) b = __ffsll((u64)~rem0) - 1;
                else if (~rem1) b = 64 + __ffsll((u64)~rem1) - 1;
                else break;
                if (lane == 0) kept[cnt] = base + b;
                ++cnt;
                if (b < 64) {
                    rem0 |= rdl64(ax, b) | (1ull << b);
                    rem1 |= rdl64(ay, b);
                    k0 |= 1ull << b;
                } else {
                    int bb = b - 64;
                    rem0 |= rdl64(bx_, bb);
                    rem1 |= rdl64(by_, bb) | (1ull << bb);
                    k1 |= 1ull << bb;
                }
            }
            if (cnt >= POSTN) break;
            u64 f0 = 0ull, f1 = 0ull, m0 = k0, m1 = k1;
            while (m0 | m1) {
                int idx[16];
                #pragma unroll
                for (int j = 0; j < 16; ++j) {
                    int b = -1;
                    if (m0) { b = __ffsll(m0) - 1; m0 &= m0 - 1; }
                    else if (m1) { b = 64 + __ffsll(m1) - 1; m1 &= m1 - 1; }
                    idx[j] = b;
                }
                u64 v0[16], v1[16];
                #pragma unroll
                for (int j = 0; j < 16; ++j) {
                    v0[j] = 0ull; v1[j] = 0ull;
                    if (idx[j] >= 0) {
                        const u64* row = mat + (size_t)(base + idx[j]) * NWORDS;
                        v0[j] = ald64(row + lane);
                        if (lane < NWORDS - 64) v1[j] = ald64(row + 64 + lane);
                    }
                }
                #pragma unroll
                for (int j = 0; j < 16; ++j) { f0 |= v0[j]; f1 |= v1[j]; }
            }
            r0 |= f0; r1 |= f1;
        }
        for (int r = lane; r < POSTN; r += 64) {
            float4 b2 = make_float4(0.f, 0.f, 0.f, 0.f);
            if (r < cnt) b2 = ldf4(&tb[kept[r]]);
            float* o = out + r * 5;
            o[0] = 0.f; o[1] = b2.x; o[2] = b2.y; o[3] = b2.z; o[4] = b2.w;
        }
    }
}

// ---------------- host launcher ----------------
extern "C" void kernel_launch(void* const* d_in, const int* in_sizes, int n_in,
                              void* d_out, int out_size, void* d_ws, size_t ws_size,
                              hipStream_t stream) {
    const float* scores = (const float*)d_in[0];
    const float* deltas = (const float*)d_in[1];
    const float* iminfo = (const float*)d_in[2];
    float* out = (float*)d_out;

    char* ws = (char*)d_ws;
    // header [0,8192) zeroed by one async memset each launch
    u32* bar    = (u32*)(ws + 0);          // 64
    u32* hist1  = (u32*)(ws + 64);         // 1024
    u32* hist2  = (u32*)(ws + 1088);       // 1024
    u32* segctr = (u32*)(ws + 2112);       // 2048 (8 ctrs, 128B apart)
    u64* vmask  = (u64*)(ws + 4160);       // 768
    u32* keys   = (u32*)(ws + 8192);       // 884736
    u64* cand   = (u64*)(ws + 892928);     // 65536
    float4* tb  = (float4*)(ws + 958464);  // 96256
    u64* mat    = (u64*)(ws + 1054720);    // 6016*94*8 = 4524032 -> ends 5578752

    hipMemsetAsync(ws, 0, 8192, stream);
    fused_kernel<<<GRID, 256, 0, stream>>>(scores, deltas, iminfo, out,
                                           bar, hist1, hist2, segctr, vmask,
                                           keys, cand, tb, mat);
}

// Round 10
// 261.851 us; speedup vs baseline: 3.3000x; 1.0547x over previous
//
#include <hip/hip_runtime.h>

// ---------------- problem constants ----------------
#define N_ANCH 221184      // H*W*A = 128*192*9
#define HW     24576       // H*W
#define Wd     192
#define AA     9
#define TOPN   6000
#define POSTN  300
#define NWORDS 94          // ceil(6016/64) removal words (bit per box)
#define NW2    96          // mat row stride in u64 (2 pad words, never written)
#define NCHUNK 24          // 6144 / 256 scan chunks
#define GRID   512
#define PERBLK 432         // N_ANCH / GRID exactly
#define SEGSZ  1024        // compact segment capacity (8 segs = 8192)
#define CAND_CAP 8192

typedef unsigned long long u64;
typedef unsigned int u32;

// anchor widths/heights (== ws2/hs2 of the reference, exact small ints)
__device__ const float c_aw[9] = {184.f,368.f,736.f,128.f,256.f,512.f, 88.f,176.f,352.f};
__device__ const float c_ah[9] = { 96.f,192.f,384.f,128.f,256.f,512.f,176.f,352.f,704.f};

// ---- agent-scope atomics: bypass L1/L2, L3 is the coherence point ----
__device__ __forceinline__ u32 ald32(const u32* p) {
    return __hip_atomic_load(p, __ATOMIC_RELAXED, __HIP_MEMORY_SCOPE_AGENT);
}
__device__ __forceinline__ void ast32(u32* p, u32 v) {
    __hip_atomic_store(p, v, __ATOMIC_RELAXED, __HIP_MEMORY_SCOPE_AGENT);
}
__device__ __forceinline__ u64 ald64(const u64* p) {
    return __hip_atomic_load(p, __ATOMIC_RELAXED, __HIP_MEMORY_SCOPE_AGENT);
}
__device__ __forceinline__ void ast64(u64* p, u64 v) {
    __hip_atomic_store(p, v, __ATOMIC_RELAXED, __HIP_MEMORY_SCOPE_AGENT);
}
__device__ __forceinline__ void stf4(float4* p, float4 v) {
    u64 lo, hi;
    float2 a = make_float2(v.x, v.y), b = make_float2(v.z, v.w);
    __builtin_memcpy(&lo, &a, 8); __builtin_memcpy(&hi, &b, 8);
    ast64((u64*)p, lo); ast64(((u64*)p) + 1, hi);
}
__device__ __forceinline__ float4 ldf4(const float4* p) {
    u64 lo = ald64((const u64*)p), hi = ald64(((const u64*)p) + 1);
    float2 a, b;
    __builtin_memcpy(&a, &lo, 8); __builtin_memcpy(&b, &hi, 8);
    return make_float4(a.x, a.y, b.x, b.y);
}

// grid barrier: arrivals fetch_add `cnt`; last arriver releases via `flag`
// (separate line, so waiter polling never contends with the arrival RMWs).
// No cache fences needed: all cross-phase data is agent-scope. __syncthreads
// drains vmcnt per wave before the arrival add. Bounded spin -> no hang.
__device__ __forceinline__ void gbar(u32* cnt, u32* flag, u32 epoch) {
    __syncthreads();
    if (threadIdx.x == 0) {
        u32 old = __hip_atomic_fetch_add(cnt, 1u, __ATOMIC_RELAXED, __HIP_MEMORY_SCOPE_AGENT);
        if (old == epoch * GRID - 1u) {
            ast32(flag, epoch);
        } else {
            int guard = 0;
            while (ald32(flag) < epoch) {
                __builtin_amdgcn_s_sleep(1);
                if (++guard > (1 << 22)) break;
            }
        }
    }
    __syncthreads();
}

// shared box decode — identical FP sequence wherever a box is materialized.
// No FMA contraction (numpy rounds mul and add separately).
__device__ __forceinline__ float4 decode_box(int a, int cell,
                                             const float* __restrict__ deltas,
                                             float info0, float info1, float info2,
                                             bool* valid) {
    int h = cell / Wd;
    int w = cell - h * Wd;
    const float* db = deltas + (size_t)(4 * a) * HW + cell;
    float dx = db[0];
    float dy = db[HW];
    float dw = db[2 * HW];
    float dh = db[3 * HW];
    dw = fminf(fmaxf(dw, -10.f), 10.f);
    dh = fminf(fmaxf(dh, -10.f), 10.f);

    float ww = c_aw[a], hh = c_ah[a];
    float cx = 16.f * (float)w + 8.f;   // exact
    float cy = 16.f * (float)h + 8.f;   // exact

    float pcx = __fadd_rn(__fmul_rn(dx, ww), cx);
    float pcy = __fadd_rn(__fmul_rn(dy, hh), cy);
    float pw  = __fmul_rn(expf(dw), ww);
    float ph  = __fmul_rn(expf(dh), hh);
    float hpw = __fmul_rn(0.5f, pw);
    float hph = __fmul_rn(0.5f, ph);
    float x1 = __fsub_rn(pcx, hpw);
    float x2 = __fadd_rn(pcx, hpw);
    float y1 = __fsub_rn(pcy, hph);
    float y2 = __fadd_rn(pcy, hph);

    float xmax = __fsub_rn(info1, 1.f);
    float ymax = __fsub_rn(info0, 1.f);
    x1 = fminf(fmaxf(x1, 0.f), xmax);
    x2 = fminf(fmaxf(x2, 0.f), xmax);
    y1 = fminf(fmaxf(y1, 0.f), ymax);
    y2 = fminf(fmaxf(y2, 0.f), ymax);

    float msz = __fmul_rn(16.f, info2);
    *valid = (__fadd_rn(__fsub_rn(x2, x1), 1.f) >= msz) &&
             (__fadd_rn(__fsub_rn(y2, y1), 1.f) >= msz);
    return make_float4(x1, y1, x2, y2);
}

// 64-bit readlane, wave-uniform index
__device__ __forceinline__ u64 rdl64(u64 v, int l) {
    u32 lo = (u32)__builtin_amdgcn_readlane((int)(u32)v, l);
    u32 hi = (u32)__builtin_amdgcn_readlane((int)(u32)(v >> 32), l);
    return ((u64)hi << 32) | (u64)lo;
}

__global__ __launch_bounds__(256, 2) void fused_kernel(
        const float* __restrict__ scores, const float* __restrict__ deltas,
        const float* __restrict__ iminfo, float* __restrict__ out,
        u32* __restrict__ bar, u32* __restrict__ flag,
        u32* __restrict__ hist1, u32* __restrict__ hist2,
        u32* __restrict__ segctr, u64* __restrict__ vmask,
        u32* __restrict__ keys, u64* __restrict__ cand,
        float4* __restrict__ tb, u64* __restrict__ mat) {
    int tid = threadIdx.x;
    int bid = blockIdx.x;
    int lane = tid & 63;
    int wv = tid >> 6;

    __shared__ u32 lh[256];
    __shared__ u32 sfx[256];
    __shared__ u32 h2w[4][256];
    __shared__ u64 stage[2048];          // 16 KB (rank phase)
    __shared__ float4 cbw[4][64];        // matrix phase
    __shared__ int kept[POSTN];          // scan phase
    __shared__ u32 sP, sRank, sT;

    float info0 = iminfo[0], info1 = iminfo[1], info2 = iminfo[2];
    int tbase = bid * PERBLK;            // exactly equal work per block

    // ---------- P0: decode keys + global 256-bin hist (LDS-aggregated) ------
    lh[tid] = 0u;
    __syncthreads();
    #pragma unroll
    for (int j = 0; j < 2; ++j) {
        int i = j * 256 + tid;
        if (i < PERBLK) {
            int t = tbase + i;
            int a = t / HW;
            int cell = t - a * HW;
            float score = scores[(AA + a) * HW + cell];
            bool valid;
            (void)decode_box(a, cell, deltas, info0, info1, info2, &valid);
            u32 sb = __float_as_uint(score);
            u32 key = valid ? ((sb & 0x80000000u) ? ~sb : (sb | 0x80000000u))
                            : 0x007FFFFFu;
            ast32(&keys[t], key);
            atomicAdd(&lh[key >> 24], 1u);
        }
    }
    __syncthreads();
    if (lh[tid]) atomicAdd(&hist1[tid], lh[tid]);
    gbar(bar, flag, 1);

    // ---------- P1 (redundant per block): suffix hist1 -> prefix P, rankP ---
    sfx[tid] = ald32(&hist1[tid]);
    __syncthreads();
    for (int d = 1; d < 256; d <<= 1) {
        u32 v = (tid + d < 256) ? sfx[tid + d] : 0u;
        __syncthreads();
        sfx[tid] += v;
        __syncthreads();
    }
    {
        u32 ge = sfx[tid];
        u32 gt = (tid < 255) ? sfx[tid + 1] : 0u;
        if (ge >= TOPN && gt < TOPN) { sP = (u32)tid; sRank = TOPN - gt; }
    }
    // ---------- P2: second-byte hist of prefix-P keys -> global hist2 -------
    for (int i = tid; i < 4 * 256; i += 256) ((u32*)h2w)[i] = 0u;
    __syncthreads();
    u32 P = sP, rankP = sRank;
    #pragma unroll
    for (int j = 0; j < 2; ++j) {
        int i = j * 256 + tid;
        if (i < PERBLK) {
            u32 k = ald32(&keys[tbase + i]);
            if ((k >> 24) == P) atomicAdd(&h2w[wv][(k >> 16) & 0xFFu], 1u);
        }
    }
    __syncthreads();
    {
        u32 s4 = h2w[0][tid] + h2w[1][tid] + h2w[2][tid] + h2w[3][tid];
        if (s4) atomicAdd(&hist2[tid], s4);
    }
    gbar(bar, flag, 2);

    // ---------- P3 (redundant per block): suffix hist2 -> threshold T -------
    sfx[tid] = ald32(&hist2[tid]);
    __syncthreads();
    for (int d = 1; d < 256; d <<= 1) {
        u32 v = (tid + d < 256) ? sfx[tid + d] : 0u;
        __syncthreads();
        sfx[tid] += v;
        __syncthreads();
    }
    {
        u32 ge = sfx[tid];
        u32 gt = (tid < 255) ? sfx[tid + 1] : 0u;
        if (ge >= rankP && gt < rankP) sT = (P << 24) | ((u32)tid << 16);
    }
    __syncthreads();
    u32 T = sT;
    // ---------- P4: compact keys >= T into 8 segments ----------
    #pragma unroll
    for (int j = 0; j < 2; ++j) {
        int i = j * 256 + tid;
        if (i < PERBLK) {
            int t = tbase + i;
            u32 k = ald32(&keys[t]);
            if (k >= T) {
                int seg = bid & 7;
                u32 pos = atomicAdd(&segctr[32 * seg], 1u);
                if (pos < SEGSZ) {
                    int a = t / HW;
                    int cell = t - a * HW;
                    u32 aidx = (u32)(cell * 9 + a);
                    ast64(&cand[seg * SEGSZ + pos], ((u64)k << 32) | (u64)(~aidx));
                }
            }
        }
    }
    gbar(bar, flag, 3);

    // ---------- P5: exact rank + scatter (512 blocks x 16 cand) ----------
    {
        u32 cc[8];
        #pragma unroll
        for (int s = 0; s < 8; ++s) {
            cc[s] = ald32(&segctr[32 * s]);
            if (cc[s] > SEGSZ) cc[s] = SEGSZ;
        }
        int part = tid & 15;
        int i = bid * 16 + (tid >> 4);          // [0, 8192)
        int iseg = i >> 10, ioff = i & 1023;
        bool active = (u32)ioff < cc[iseg];
        u64 k = active ? ald64(&cand[i]) : 0ull;
        u32 cnt = 0;
        for (int q = 0; q < 4; ++q) {
            for (int j = tid; j < 2048; j += 256) {
                int g = q * 2048 + j;
                int s_ = g >> 10, off = g & 1023;
                stage[j] = ((u32)off < cc[s_]) ? ald64(&cand[g]) : 0ull;
            }
            __syncthreads();
            const ulonglong2* sv = (const ulonglong2*)stage;
            for (int jj = part; jj < 1024; jj += 16) {
                ulonglong2 v = sv[jj];
                cnt += (v.x > k) ? 1u : 0u;
                cnt += (v.y > k) ? 1u : 0u;
            }
            __syncthreads();
        }
        cnt += __shfl_xor(cnt, 1);
        cnt += __shfl_xor(cnt, 2);
        cnt += __shfl_xor(cnt, 4);
        cnt += __shfl_xor(cnt, 8);
        if (part == 0 && active && cnt < TOPN) {
            u32 aidx = ~((u32)k);
            int a = (int)(aidx % 9u);
            int cell = (int)(aidx / 9u);
            bool valid;
            float4 box = decode_box(a, cell, deltas, info0, info1, info2, &valid);
            stf4(&tb[cnt], box);
            if ((u32)(k >> 32) != 0x007FFFFFu)
                atomicOr(&vmask[cnt >> 6], 1ull << (cnt & 63));
        }
    }
    gbar(bar, flag, 4);

    // ---------- P6: suppression bit-matrix (upper-triangle tiles) ----------
    {
        int waveid = bid * 4 + wv;
        for (int j = waveid; j < 94 * 94; j += GRID * 4) {
            int by = j / 94;
            int bx = j - by * 94;
            if (bx < by) continue;
            int c0 = bx * 64;
            {
                int col = c0 + lane;
                cbw[wv][lane] = (col < TOPN) ? ldf4(&tb[col]) : make_float4(0.f, 0.f, 0.f, 0.f);
            }
            int row = by * 64 + lane;
            if (row < TOPN) {
                float4 rb = ldf4(&tb[row]);
                float rA = (rb.z - rb.x) * (rb.w - rb.y);
                u64 mask = 0ull;
                for (int c = 0; c < 64; ++c) {
                    if (c0 + c >= TOPN) break;
                    float4 b = cbw[wv][c];
                    float lx = fmaxf(rb.x, b.x), ly = fmaxf(rb.y, b.y);
                    float rx = fminf(rb.z, b.z), ry = fminf(rb.w, b.w);
                    float iw = fmaxf(rx - lx, 0.f), ih = fmaxf(ry - ly, 0.f);
                    float inter = iw * ih;
                    float bA = (b.z - b.x) * (b.w - b.y);
                    float iou = inter / ((rA + bA) - inter);
                    if (iou > 0.7f) mask |= (1ull << c);   // NaN -> false, as numpy
                }
                ast64(&mat[(size_t)row * NW2 + bx], mask);
            }
        }
    }
    gbar(bar, flag, 5);

    // ---------- P7: greedy scan, 256-box chunks, diag prefetch 1 ahead ------
    if (bid == 0 && tid < 64) {
        u64 r0 = ~ald64(&vmask[lane]);
        u64 r1 = (lane < NWORDS - 64) ? ~ald64(&vmask[64 + lane]) : ~0ull;
        int cnt = 0;
        // prefetch chunk 0 diagonal block: lane holds rows {lane,64+lane,128+lane,192+lane}
        u64 dg[4][4];
        #pragma unroll
        for (int q = 0; q < 4; ++q) {
            const u64* rp = mat + (size_t)(q * 64 + lane) * NW2;
            dg[q][0] = ald64(rp); dg[q][1] = ald64(rp + 1);
            dg[q][2] = ald64(rp + 2); dg[q][3] = ald64(rp + 3);
        }
        for (int c = 0; c < NCHUNK; ++c) {
            u64 nd[4][4];
            #pragma unroll
            for (int q = 0; q < 4; ++q) { nd[q][0]=0; nd[q][1]=0; nd[q][2]=0; nd[q][3]=0; }
            if (c + 1 < NCHUNK) {   // unconditional prefetch: off the critical path
                int nb = (c + 1) * 256, nw = 4 * (c + 1);
                #pragma unroll
                for (int q = 0; q < 4; ++q) {
                    const u64* rp = mat + (size_t)(nb + q * 64 + lane) * NW2 + nw;
                    nd[q][0] = ald64(rp); nd[q][1] = ald64(rp + 1);
                    nd[q][2] = ald64(rp + 2); nd[q][3] = ald64(rp + 3);
                }
            }
            int w0 = 4 * c;
            u64 s0 = (w0     < 64) ? rdl64(r0, w0)     : rdl64(r1, w0 - 64);
            u64 s1 = (w0 + 1 < 64) ? rdl64(r0, w0 + 1) : rdl64(r1, w0 - 63);
            u64 s2 = (w0 + 2 < 64) ? rdl64(r0, w0 + 2) : rdl64(r1, w0 - 62);
            u64 s3 = (w0 + 3 < 64) ? rdl64(r0, w0 + 3) : rdl64(r1, w0 - 61);
            if ((s0 & s1 & s2 & s3) != ~0ull) {
                int base = c * 256;
                u64 rem0 = s0, rem1 = s1, rem2 = s2, rem3 = s3;
                u64 km0 = 0, km1 = 0, km2 = 0, km3 = 0;
                while (cnt < POSTN) {
                    int b;
                    if (~rem0) b = __ffsll((u64)~rem0) - 1;
                    else if (~rem1) b = 64  + __ffsll((u64)~rem1) - 1;
                    else if (~rem2) b = 128 + __ffsll((u64)~rem2) - 1;
                    else if (~rem3) b = 192 + __ffsll((u64)~rem3) - 1;
                    else break;
                    if (lane == 0) kept[cnt] = base + b;
                    ++cnt;
                    int q = b >> 6, l = b & 63;
                    u64 v0, v1, v2, v3;
                    if (q == 0)      { v0=dg[0][0]; v1=dg[0][1]; v2=dg[0][2]; v3=dg[0][3]; }
                    else if (q == 1) { v0=dg[1][0]; v1=dg[1][1]; v2=dg[1][2]; v3=dg[1][3]; }
                    else if (q == 2) { v0=dg[2][0]; v1=dg[2][1]; v2=dg[2][2]; v3=dg[2][3]; }
                    else             { v0=dg[3][0]; v1=dg[3][1]; v2=dg[3][2]; v3=dg[3][3]; }
                    rem0 |= rdl64(v0, l); rem1 |= rdl64(v1, l);
                    rem2 |= rdl64(v2, l); rem3 |= rdl64(v3, l);
                    u64 bit = 1ull << l;
                    if (q == 0)      { rem0 |= bit; km0 |= bit; }
                    else if (q == 1) { rem1 |= bit; km1 |= bit; }
                    else if (q == 2) { rem2 |= bit; km2 |= bit; }
                    else             { rem3 |= bit; km3 |= bit; }
                }
                if (cnt >= POSTN) break;
                // propagate kept rows into lane-owned removal words, 16/drain
                u64 f0 = 0ull, f1 = 0ull;
                while (km0 | km1 | km2 | km3) {
                    int idx[16];
                    #pragma unroll
                    for (int j = 0; j < 16; ++j) {
                        int b = -1;
                        if (km0)      { b = __ffsll(km0) - 1;        km0 &= km0 - 1; }
                        else if (km1) { b = 64  + __ffsll(km1) - 1;  km1 &= km1 - 1; }
                        else if (km2) { b = 128 + __ffsll(km2) - 1;  km2 &= km2 - 1; }
                        else if (km3) { b = 192 + __ffsll(km3) - 1;  km3 &= km3 - 1; }
                        idx[j] = b;
                    }
                    u64 a0[16], a1[16];
                    #pragma unroll
                    for (int j = 0; j < 16; ++j) {
                        a0[j] = 0ull; a1[j] = 0ull;
                        if (idx[j] >= 0) {
                            const u64* row = mat + (size_t)(base + idx[j]) * NW2;
                            a0[j] = ald64(row + lane);
                            if (lane < NWORDS - 64) a1[j] = ald64(row + 64 + lane);
                        }
                    }
                    #pragma unroll
                    for (int j = 0; j < 16; ++j) { f0 |= a0[j]; f1 |= a1[j]; }
                }
                r0 |= f0; r1 |= f1;
            }
            #pragma unroll
            for (int q = 0; q < 4; ++q) {
                dg[q][0]=nd[q][0]; dg[q][1]=nd[q][1]; dg[q][2]=nd[q][2]; dg[q][3]=nd[q][3];
            }
        }
        for (int r = lane; r < POSTN; r += 64) {
            float4 b2 = make_float4(0.f, 0.f, 0.f, 0.f);
            if (r < cnt) b2 = ldf4(&tb[kept[r]]);
            float* o = out + r * 5;
            o[0] = 0.f; o[1] = b2.x; o[2] = b2.y; o[3] = b2.z; o[4] = b2.w;
        }
    }
}

// ---------------- host launcher ----------------
extern "C" void kernel_launch(void* const* d_in, const int* in_sizes, int n_in,
                              void* d_out, int out_size, void* d_ws, size_t ws_size,
                              hipStream_t stream) {
    const float* scores = (const float*)d_in[0];
    const float* deltas = (const float*)d_in[1];
    const float* iminfo = (const float*)d_in[2];
    float* out = (float*)d_out;

    char* ws = (char*)d_ws;
    // header [0,8192) zeroed by one async memset each launch
    u32* bar    = (u32*)(ws + 0);          // 64
    u32* flag   = (u32*)(ws + 128);        // 64 (separate line from bar)
    u32* hist1  = (u32*)(ws + 256);        // 1024
    u32* hist2  = (u32*)(ws + 1280);       // 1024
    u32* segctr = (u32*)(ws + 2304);       // 1024 (8 ctrs, 128B apart)
    u64* vmask  = (u64*)(ws + 3328);       // 768
    u32* keys   = (u32*)(ws + 8192);       // 884736
    u64* cand   = (u64*)(ws + 892928);     // 65536
    float4* tb  = (float4*)(ws + 958464);  // 96256
    u64* mat    = (u64*)(ws + 1054720);    // 6144*96*8 = 4718592 -> ends 5773312

    hipMemsetAsync(ws, 0, 8192, stream);
    fused_kernel<<<GRID, 256, 0, stream>>>(scores, deltas, iminfo, out,
                                           bar, flag, hist1, hist2, segctr, vmask,
                                           keys, cand, tb, mat);
}